// Round 2
// baseline (179.306 us; speedup 1.0000x reference)
//
#include <hip/hip_runtime.h>
#include <math.h>

#define BB 64
#define CC 128
#define KK 64
#define NN 4096
#define PCH 128            // pixels per chunk
#define NCH 4              // chunks per block
#define SLAB (PCH*NCH)     // 512 pixels per block

typedef __attribute__((ext_vector_type(8))) short short8;
typedef __attribute__((ext_vector_type(16))) float f32x16;

// fp32 -> bf16 bits, round-to-nearest-even
__device__ __forceinline__ unsigned f2bf(float f) {
    unsigned u = __float_as_uint(f);
    return (u + 0x7fffu + ((u >> 16) & 1u)) >> 16;
}

__device__ __forceinline__ short8 pack8(float4 a, float4 b) {
    short8 r;
    r[0]=(short)f2bf(a.x); r[1]=(short)f2bf(a.y); r[2]=(short)f2bf(a.z); r[3]=(short)f2bf(a.w);
    r[4]=(short)f2bf(b.x); r[5]=(short)f2bf(b.y); r[6]=(short)f2bf(b.z); r[7]=(short)f2bf(b.w);
    return r;
}

// ---------------- Phase 1: logits -> softmax -> vlad partials (MFMA bf16) ----
// MFMA 32x32x16 layout assumptions (gfx950):
//   A[m][k]: lane holds m = l&31, k = 8*(l>>5)+j (j=0..7 contiguous)
//   B[k][n]: lane holds n = l&31, k = 8*(l>>5)+j
//   C/D:     col = l&31, row = (r&3) + 8*(r>>2) + 4*(l>>5)   [verified m74/m101]
// LDS swizzle: byte chunk (16B) index ch' = ch ^ (row & 7)  [m201 st-swizzle]
__global__ __launch_bounds__(512, 4) void nv_phase1(
    const float* __restrict__ x,      // [B][C][N]
    const float* __restrict__ convw,  // [K][C]
    float* __restrict__ vlad,         // [B][K][C] accumulated via atomics (d_out)
    float* __restrict__ asum_g)       // [B][K]    accumulated via atomics (ws)
{
    __shared__ alignas(16) unsigned short xs[PCH*CC];  // bf16 x, [n][c], swizzled
    __shared__ alignas(16) unsigned short al[KK*PCH];  // bf16 a, [k][n], swizzled
    __shared__ float redmx[2][PCH];
    __shared__ float redsm[2][PCH];
    __shared__ float asred[2][2][16][4];               // [kt][q][r][nt]

    const int t  = threadIdx.x;
    const int b  = blockIdx.y;
    const int n_slab = blockIdx.x * SLAB;
    const int l   = t & 63;
    const int wid = t >> 6;
    const int ln  = l & 31;
    const int q   = l >> 5;
    const int kt  = wid & 1;          // logits k-tile (0..1)
    const int nt  = wid >> 1;         // logits n-tile (0..3)
    const int ct  = wid & 3;          // vlad c-tile (0..3)
    const int kt2 = wid >> 2;         // vlad k-tile (0..1)
    const int r4  = t & 3;

    const float* xb = x + (size_t)b * CC * NN;

    // ---- preload conv_w fragments (A of logits), reused for all chunks ----
    short8 wfrag[8];
    {
        const float* wr = convw + (size_t)(ln + 32*kt) * CC + 8*q;
#pragma unroll
        for (int cs = 0; cs < 8; ++cs) {
            float4 a  = *(const float4*)(wr + 16*cs);
            float4 bb = *(const float4*)(wr + 16*cs + 4);
            wfrag[cs] = pack8(a, bb);
        }
    }

    f32x16 vacc;
#pragma unroll
    for (int i = 0; i < 16; ++i) vacc[i] = 0.f;
    float asum_l[16];
#pragma unroll
    for (int i = 0; i < 16; ++i) asum_l[i] = 0.f;

    const int n_ = ln + 32*nt;        // this thread's softmax pixel (chunk-local)
    const int k2 = ln + 32*kt2;       // this thread's vlad k (B operand row block)

#pragma unroll 1
    for (int chk = 0; chk < NCH; ++chk) {
        const int gn0 = n_slab + chk * PCH;

        // ---- stage x chunk -> xs[n][c] bf16 via quad 4x4 shuffle transpose ----
#pragma unroll
        for (int i = 0; i < 8; ++i) {
            int u  = (t >> 2) + 128 * i;    // unit id 0..1023
            int cQ = u >> 5;                // c-quad 0..31
            int nQ = u & 31;                // n-quad 0..31
            float4 v = *(const float4*)(xb + (size_t)(4*cQ + r4) * NN + gn0 + 4*nQ);
            unsigned d0 = f2bf(v.x) | (f2bf(v.y) << 16);   // (n0,n1) @ c
            unsigned d1 = f2bf(v.z) | (f2bf(v.w) << 16);   // (n2,n3) @ c
            unsigned p0 = (unsigned)__shfl_xor((int)d0, 1);
            unsigned p1 = (unsigned)__shfl_xor((int)d1, 1);
            unsigned e, f;
            if (r4 & 1) { e = (p0 >> 16) | (d0 & 0xffff0000u);   // cpair @ n1
                          f = (p1 >> 16) | (d1 & 0xffff0000u); } // cpair @ n3
            else        { e = (d0 & 0xffffu) | (p0 << 16);       // cpair @ n0
                          f = (d1 & 0xffffu) | (p1 << 16); }     // cpair @ n2
            unsigned s  = (unsigned)__shfl_xor((int)((r4 & 2) ? e : f), 2);
            unsigned w0 = (r4 & 2) ? s : e;   // (c0,c1) @ n=4nQ+r4
            unsigned w1 = (r4 & 2) ? f : s;   // (c2,c3) @ n=4nQ+r4
            int nn  = 4*nQ + r4;
            int chp = (cQ >> 1) ^ (nn & 7);
            *(uint2*)((char*)xs + nn*256 + (chp << 4) + (cQ & 1)*8) = make_uint2(w0, w1);
        }
        __syncthreads();

        // ---- logits: D[k][n] = W x X, wave tile (kt, nt) ----
        f32x16 lacc;
#pragma unroll
        for (int i = 0; i < 16; ++i) lacc[i] = 0.f;
#pragma unroll
        for (int cs = 0; cs < 8; ++cs) {
            int chp = (2*cs + q) ^ (n_ & 7);
            short8 bf = *(const short8*)((const char*)xs + n_*256 + (chp << 4));
            lacc = __builtin_amdgcn_mfma_f32_32x32x16_bf16(wfrag[cs], bf, lacc, 0, 0, 0);
        }

        // ---- softmax over k per pixel n_ (lane holds 16 of 32 k's in tile kt) ----
        float mx = lacc[0];
#pragma unroll
        for (int i = 1; i < 16; ++i) mx = fmaxf(mx, lacc[i]);
        mx = fmaxf(mx, __shfl_xor(mx, 32));
        if (q == 0) redmx[kt][n_] = mx;
        __syncthreads();
        float m = fmaxf(redmx[0][n_], redmx[1][n_]);
        float ssum = 0.f;
#pragma unroll
        for (int i = 0; i < 16; ++i) { float e2 = __expf(lacc[i] - m); lacc[i] = e2; ssum += e2; }
        ssum += __shfl_xor(ssum, 32);
        if (q == 0) redsm[kt][n_] = ssum;
        __syncthreads();
        float inv = 1.0f / (redsm[0][n_] + redsm[1][n_]);
#pragma unroll
        for (int i = 0; i < 16; ++i) {
            float a = lacc[i] * inv;
            asum_l[i] += a;
            int k_ = 32*kt + 4*q + (i & 3) + 8*(i >> 2);
            al[k_*128 + (((n_ >> 3) ^ (k_ & 7)) << 3) + (n_ & 7)] = (unsigned short)f2bf(a);
        }
        __syncthreads();

        // ---- vlad: D[c][k] += X x A^T, wave tile (ct, kt2); X from global (L2-hot) ----
        const float* xr = xb + (size_t)(ln + 32*ct) * NN + gn0 + 8*q;
#pragma unroll
        for (int ns = 0; ns < 8; ++ns) {
            float4 u0 = *(const float4*)(xr + 16*ns);
            float4 u1 = *(const float4*)(xr + 16*ns + 4);
            short8 af = pack8(u0, u1);
            int chp = (2*ns + q) ^ (k2 & 7);
            short8 bf = *(const short8*)((const char*)al + k2*256 + (chp << 4));
            vacc = __builtin_amdgcn_mfma_f32_32x32x16_bf16(af, bf, vacc, 0, 0, 0);
        }
        // next chunk's staging is safe: xs reads all precede sync after logits;
        // al(i+1) writes come after two more barriers (all waves past vlad(i)).
    }

    // ---- epilogue: vlad partials -> global atomics ----
    {
        float* vb = vlad + (size_t)b * KK * CC + (size_t)k2 * CC + 32*ct + 4*q;
#pragma unroll
        for (int i = 0; i < 16; ++i)
            atomicAdd(&vb[(i & 3) + 8*(i >> 2)], vacc[i]);
    }

    // ---- asum: butterfly over 32 pixel-lanes, cross-wave LDS, 64 atomics ----
#pragma unroll
    for (int i = 0; i < 16; ++i) {
        float v = asum_l[i];
        v += __shfl_xor(v, 1);  v += __shfl_xor(v, 2);  v += __shfl_xor(v, 4);
        v += __shfl_xor(v, 8);  v += __shfl_xor(v, 16);
        asum_l[i] = v;
    }
    if (ln == 0) {
#pragma unroll
        for (int i = 0; i < 16; ++i) asred[kt][q][i][nt] = asum_l[i];
    }
    __syncthreads();
    if (t < 64) {
        int kt_ = t >> 5, q_ = (t >> 4) & 1, r_ = t & 15;
        int k_ = 32*kt_ + 4*q_ + (r_ & 3) + 8*(r_ >> 2);
        float s = asred[kt_][q_][r_][0] + asred[kt_][q_][r_][1]
                + asred[kt_][q_][r_][2] + asred[kt_][q_][r_][3];
        atomicAdd(&asum_g[b * KK + k_], s);
    }
}

// ---------------- Phase 2: centroid subtract + intra + global L2 normalize ---
__global__ __launch_bounds__(256) void nv_phase2(
    float* __restrict__ vlad,        // [B][K][C] in/out (d_out)
    const float* __restrict__ asum,  // [B][K]
    const float* __restrict__ cent)  // [K][C]
{
    __shared__ float gred[4];
    const int b    = blockIdx.x;
    const int w    = threadIdx.x >> 6;   // wave 0..3 -> 16 rows each
    const int lane = threadIdx.x & 63;

    float v[32];
    float gsum = 0.f;
#pragma unroll
    for (int r = 0; r < 16; r++) {
        int k = w * 16 + r;
        float a  = asum[b * KK + k];
        float x0 = vlad[((size_t)b * KK + k) * CC + lane]      - a * cent[k * CC + lane];
        float x1 = vlad[((size_t)b * KK + k) * CC + lane + 64] - a * cent[k * CC + lane + 64];
        float ss = x0 * x0 + x1 * x1;
#pragma unroll
        for (int m = 1; m < 64; m <<= 1) ss += __shfl_xor(ss, m, 64);
        float rn = 1.0f / fmaxf(sqrtf(ss), 1e-12f);
        v[2 * r]     = x0 * rn;
        v[2 * r + 1] = x1 * rn;
        gsum += ss * rn * rn;
    }
    if (lane == 0) gred[w] = gsum;
    __syncthreads();
    float g  = gred[0] + gred[1] + gred[2] + gred[3];
    float gs = 1.0f / fmaxf(sqrtf(g), 1e-12f);
#pragma unroll
    for (int r = 0; r < 16; r++) {
        int k = w * 16 + r;
        vlad[((size_t)b * KK + k) * CC + lane]      = v[2 * r]     * gs;
        vlad[((size_t)b * KK + k) * CC + lane + 64] = v[2 * r + 1] * gs;
    }
}

extern "C" void kernel_launch(void* const* d_in, const int* in_sizes, int n_in,
                              void* d_out, int out_size, void* d_ws, size_t ws_size,
                              hipStream_t stream) {
    const float* x     = (const float*)d_in[0];
    const float* convw = (const float*)d_in[1];
    const float* cent  = (const float*)d_in[2];
    float* out  = (float*)d_out;
    float* asum = (float*)d_ws;   // B*K floats = 16 KiB

    hipMemsetAsync(out,  0, (size_t)BB * KK * CC * sizeof(float), stream);
    hipMemsetAsync(asum, 0, (size_t)BB * KK * sizeof(float), stream);

    nv_phase1<<<dim3(NN / SLAB, BB), 512, 0, stream>>>(x, convw, out, asum);
    nv_phase2<<<BB, 256, 0, stream>>>(out, asum, cent);
}

// Round 3
// 175.380 us; speedup vs baseline: 1.0224x; 1.0224x over previous
//
#include <hip/hip_runtime.h>
#include <math.h>

#define BB 64
#define CC 128
#define KK 64
#define NN 4096
#define PCH 128            // pixels per chunk
#define NCH 4              // chunks per block
#define SLAB (PCH*NCH)     // 512 pixels per block

typedef __attribute__((ext_vector_type(8))) short short8;
typedef __attribute__((ext_vector_type(16))) float f32x16;

// fp32 -> bf16 bits, round-to-nearest-even
__device__ __forceinline__ unsigned f2bf(float f) {
    unsigned u = __float_as_uint(f);
    return (u + 0x7fffu + ((u >> 16) & 1u)) >> 16;
}

__device__ __forceinline__ short8 pack8(float4 a, float4 b) {
    short8 r;
    r[0]=(short)f2bf(a.x); r[1]=(short)f2bf(a.y); r[2]=(short)f2bf(a.z); r[3]=(short)f2bf(a.w);
    r[4]=(short)f2bf(b.x); r[5]=(short)f2bf(b.y); r[6]=(short)f2bf(b.z); r[7]=(short)f2bf(b.w);
    return r;
}

// LDS-only fence barrier: drains ds ops for cross-wave visibility but leaves
// global loads (vmcnt) in flight across the barrier (prefetch survives).
#define LDS_FENCE_BARRIER() do {                                  \
    asm volatile("s_waitcnt lgkmcnt(0)" ::: "memory");            \
    __builtin_amdgcn_s_barrier();                                 \
} while (0)

// ---------------- Phase 1: logits -> softmax -> vlad partials (MFMA bf16) ----
// MFMA 32x32x16 layouts (verified in round 2, absmax 1.2e-4 PASS):
//   A[m][k]: lane m=l&31, k=8*(l>>5)+j ; B[k][n]: lane n=l&31, k=8*(l>>5)+j
//   C/D: col=l&31, row=(r&3)+8*(r>>2)+4*(l>>5)
// LDS 16B-chunk XOR swizzle: chunk' = chunk ^ (row & 7)
__global__ __launch_bounds__(512, 4) void nv_phase1(
    const float* __restrict__ x,      // [B][C][N]
    const float* __restrict__ convw,  // [K][C]
    float* __restrict__ vlad,         // [B][K][C] accumulated via atomics (d_out)
    float* __restrict__ asum_g)       // [B][K]    accumulated via atomics (ws)
{
    __shared__ alignas(16) unsigned short xs[PCH*CC];  // 32 KB bf16 x, [n][c], swizzled
    __shared__ alignas(16) unsigned short xc[CC*PCH];  // 32 KB bf16 x, [c][n], swizzled
    __shared__ float redsm[2][PCH];                    // softmax denom cross-wave
    __shared__ float asred[2][2][16][4];               // [kt][q][r][nt]

    unsigned short* al = xs;   // a[k][n] bf16 (16 KB) aliases xs rows 0..63:
                               // xs dead after logits; al dead before next stage.

    const int t  = threadIdx.x;
    const int b  = blockIdx.y;
    const int n_slab = blockIdx.x * SLAB;
    const int l   = t & 63;
    const int wid = t >> 6;
    const int ln  = l & 31;
    const int q   = l >> 5;
    const int kt  = wid & 1;          // logits k-tile
    const int nt  = wid >> 1;         // logits n-tile
    const int ct  = wid & 3;          // vlad c-tile
    const int kt2 = wid >> 2;         // vlad k-tile
    const int r4  = t & 3;

    const float* xb = x + (size_t)b * CC * NN;
    const int n_ = ln + 32*nt;        // softmax pixel (chunk-local)
    const int c2 = ln + 32*ct;        // vlad A row (channel)
    const int k2 = ln + 32*kt2;       // vlad B row (cluster)

    // ---- prologue: issue chunk-0 staging loads (held packed in regs) ----
    unsigned pf0[8], pf1[8];
#pragma unroll
    for (int i = 0; i < 8; ++i) {
        int u = (t >> 2) + 128 * i, cQ = u >> 5, nQ = u & 31;
        float4 v = *(const float4*)(xb + (size_t)(4*cQ + r4) * NN + n_slab + 4*nQ);
        pf0[i] = f2bf(v.x) | (f2bf(v.y) << 16);
        pf1[i] = f2bf(v.z) | (f2bf(v.w) << 16);
    }

    // ---- preload conv_w fragments (A of logits), reused for all chunks ----
    short8 wfrag[8];
    {
        const float* wr = convw + (size_t)(ln + 32*kt) * CC + 8*q;
#pragma unroll
        for (int cs = 0; cs < 8; ++cs) {
            float4 a  = *(const float4*)(wr + 16*cs);
            float4 bb = *(const float4*)(wr + 16*cs + 4);
            wfrag[cs] = pack8(a, bb);
        }
    }

    f32x16 vacc;
#pragma unroll
    for (int i = 0; i < 16; ++i) vacc[i] = 0.f;
    float asum_l[16];
#pragma unroll
    for (int i = 0; i < 16; ++i) asum_l[i] = 0.f;

#pragma unroll 1
    for (int chk = 0; chk < NCH; ++chk) {
        // ---- A: write xs[n][c] + xc[c][n] from prefetch regs ----
#pragma unroll
        for (int i = 0; i < 8; ++i) {
            int u = (t >> 2) + 128 * i, cQ = u >> 5, nQ = u & 31;
            unsigned d0 = pf0[i], d1 = pf1[i];
            // xc: straight write, 4 consecutive n at row c
            int c = 4*cQ + r4;
            *(uint2*)((char*)xc + c*256 + ((((nQ >> 1) ^ (c & 7)) << 4) | ((nQ & 1) * 8)))
                = make_uint2(d0, d1);
            // xs: quad 4x4 shuffle transpose (verified round 2)
            unsigned q0 = (unsigned)__shfl_xor((int)d0, 1);
            unsigned q1 = (unsigned)__shfl_xor((int)d1, 1);
            unsigned e, f;
            if (r4 & 1) { e = (q0 >> 16) | (d0 & 0xffff0000u);
                          f = (q1 >> 16) | (d1 & 0xffff0000u); }
            else        { e = (d0 & 0xffffu) | (q0 << 16);
                          f = (d1 & 0xffffu) | (q1 << 16); }
            unsigned s2 = (unsigned)__shfl_xor((int)((r4 & 2) ? e : f), 2);
            unsigned w0 = (r4 & 2) ? s2 : e;
            unsigned w1 = (r4 & 2) ? f : s2;
            int nn  = 4*nQ + r4;
            int chp = (cQ >> 1) ^ (nn & 7);
            *(uint2*)((char*)xs + nn*256 + (chp << 4) + (cQ & 1)*8) = make_uint2(w0, w1);
        }
        // ---- B: issue next chunk's staging loads (hidden under C/D/E/F) ----
        if (chk + 1 < NCH) {
            const int gn1 = n_slab + (chk + 1) * PCH;
#pragma unroll
            for (int i = 0; i < 8; ++i) {
                int u = (t >> 2) + 128 * i, cQ = u >> 5, nQ = u & 31;
                float4 v = *(const float4*)(xb + (size_t)(4*cQ + r4) * NN + gn1 + 4*nQ);
                pf0[i] = f2bf(v.x) | (f2bf(v.y) << 16);
                pf1[i] = f2bf(v.z) | (f2bf(v.w) << 16);
            }
        }
        LDS_FENCE_BARRIER();   // #1: xs, xc visible

        // ---- C: logits D[k][n] = W x X ----
        f32x16 lacc;
#pragma unroll
        for (int i = 0; i < 16; ++i) lacc[i] = 0.f;
#pragma unroll
        for (int cs = 0; cs < 8; ++cs) {
            int chp = (2*cs + q) ^ (n_ & 7);
            short8 bf = *(const short8*)((const char*)xs + n_*256 + (chp << 4));
            lacc = __builtin_amdgcn_mfma_f32_32x32x16_bf16(wfrag[cs], bf, lacc, 0, 0, 0);
        }

        // ---- D: softmax over k, no max-sub (|logit| <~ 8, exp safe in fp32) ----
        float ssum = 0.f;
#pragma unroll
        for (int i = 0; i < 16; ++i) { float e2 = __expf(lacc[i]); lacc[i] = e2; ssum += e2; }
        ssum += __shfl_xor(ssum, 32);
        if (q == 0) redsm[kt][n_] = ssum;
        LDS_FENCE_BARRIER();   // #2: denom visible

        // ---- E: scale, store a -> al (aliased), accumulate asum ----
        float inv = 1.0f / (redsm[0][n_] + redsm[1][n_]);
#pragma unroll
        for (int i = 0; i < 16; ++i) {
            float a = lacc[i] * inv;
            asum_l[i] += a;
            int k_ = 32*kt + 4*q + (i & 3) + 8*(i >> 2);
            al[k_*128 + ((((n_ >> 3) ^ (k_ & 7)) << 3) | (n_ & 7))] = (unsigned short)f2bf(a);
        }
        LDS_FENCE_BARRIER();   // #3: al ready

        // ---- F: vlad D[c][k] += X x A^T, both operands from LDS ----
#pragma unroll
        for (int ns = 0; ns < 8; ++ns) {
            int ca = (2*ns + q) ^ (c2 & 7);
            short8 af = *(const short8*)((const char*)xc + c2*256 + (ca << 4));
            int cb = (2*ns + q) ^ (k2 & 7);
            short8 bf = *(const short8*)((const char*)al + k2*256 + (cb << 4));
            vacc = __builtin_amdgcn_mfma_f32_32x32x16_bf16(af, bf, vacc, 0, 0, 0);
        }
        LDS_FENCE_BARRIER();   // #4: LDS free for next chunk's staging writes
    }

    // ---- epilogue: vlad partials -> global atomics ----
    {
        float* vb = vlad + (size_t)b * KK * CC + (size_t)k2 * CC + 32*ct + 4*q;
#pragma unroll
        for (int i = 0; i < 16; ++i)
            atomicAdd(&vb[(i & 3) + 8*(i >> 2)], vacc[i]);
    }

    // ---- asum: butterfly over 32 pixel-lanes, cross-wave LDS, 64 atomics ----
#pragma unroll
    for (int i = 0; i < 16; ++i) {
        float v = asum_l[i];
        v += __shfl_xor(v, 1);  v += __shfl_xor(v, 2);  v += __shfl_xor(v, 4);
        v += __shfl_xor(v, 8);  v += __shfl_xor(v, 16);
        asum_l[i] = v;
    }
    if (ln == 0) {
#pragma unroll
        for (int i = 0; i < 16; ++i) asred[kt][q][i][nt] = asum_l[i];
    }
    __syncthreads();
    if (t < 64) {
        int kt_ = t >> 5, q_ = (t >> 4) & 1, r_ = t & 15;
        int k_ = 32*kt_ + 4*q_ + (r_ & 3) + 8*(r_ >> 2);
        float s = asred[kt_][q_][r_][0] + asred[kt_][q_][r_][1]
                + asred[kt_][q_][r_][2] + asred[kt_][q_][r_][3];
        atomicAdd(&asum_g[b * KK + k_], s);
    }
}

// ---------------- Phase 2: centroid subtract + intra + global L2 normalize ---
__global__ __launch_bounds__(256) void nv_phase2(
    float* __restrict__ vlad,        // [B][K][C] in/out (d_out)
    const float* __restrict__ asum,  // [B][K]
    const float* __restrict__ cent)  // [K][C]
{
    __shared__ float gred[4];
    const int b    = blockIdx.x;
    const int w    = threadIdx.x >> 6;   // wave 0..3 -> 16 rows each
    const int lane = threadIdx.x & 63;

    float v[32];
    float gsum = 0.f;
#pragma unroll
    for (int r = 0; r < 16; r++) {
        int k = w * 16 + r;
        float a  = asum[b * KK + k];
        float x0 = vlad[((size_t)b * KK + k) * CC + lane]      - a * cent[k * CC + lane];
        float x1 = vlad[((size_t)b * KK + k) * CC + lane + 64] - a * cent[k * CC + lane + 64];
        float ss = x0 * x0 + x1 * x1;
#pragma unroll
        for (int m = 1; m < 64; m <<= 1) ss += __shfl_xor(ss, m, 64);
        float rn = 1.0f / fmaxf(sqrtf(ss), 1e-12f);
        v[2 * r]     = x0 * rn;
        v[2 * r + 1] = x1 * rn;
        gsum += ss * rn * rn;
    }
    if (lane == 0) gred[w] = gsum;
    __syncthreads();
    float g  = gred[0] + gred[1] + gred[2] + gred[3];
    float gs = 1.0f / fmaxf(sqrtf(g), 1e-12f);
#pragma unroll
    for (int r = 0; r < 16; r++) {
        int k = w * 16 + r;
        vlad[((size_t)b * KK + k) * CC + lane]      = v[2 * r]     * gs;
        vlad[((size_t)b * KK + k) * CC + lane + 64] = v[2 * r + 1] * gs;
    }
}

extern "C" void kernel_launch(void* const* d_in, const int* in_sizes, int n_in,
                              void* d_out, int out_size, void* d_ws, size_t ws_size,
                              hipStream_t stream) {
    const float* x     = (const float*)d_in[0];
    const float* convw = (const float*)d_in[1];
    const float* cent  = (const float*)d_in[2];
    float* out  = (float*)d_out;
    float* asum = (float*)d_ws;   // B*K floats = 16 KiB

    hipMemsetAsync(out,  0, (size_t)BB * KK * CC * sizeof(float), stream);
    hipMemsetAsync(asum, 0, (size_t)BB * KK * sizeof(float), stream);

    nv_phase1<<<dim3(NN / SLAB, BB), 512, 0, stream>>>(x, convw, out, asum);
    nv_phase2<<<BB, 256, 0, stream>>>(out, asum, cent);
}

// Round 4
// 175.337 us; speedup vs baseline: 1.0226x; 1.0002x over previous
//
#include <hip/hip_runtime.h>
#include <math.h>

#define BB 64
#define CC 128
#define KK 64
#define NN 4096
#define PCH 128            // pixels per chunk
#define NCH 4              // chunks per block
#define SLAB (PCH*NCH)     // 512 pixels per block

typedef __attribute__((ext_vector_type(8))) short short8;
typedef __attribute__((ext_vector_type(16))) float f32x16;

// fp32 -> bf16 bits, round-to-nearest-even
__device__ __forceinline__ unsigned f2bf(float f) {
    unsigned u = __float_as_uint(f);
    return (u + 0x7fffu + ((u >> 16) & 1u)) >> 16;
}

__device__ __forceinline__ short8 pack8(float4 a, float4 b) {
    short8 r;
    r[0]=(short)f2bf(a.x); r[1]=(short)f2bf(a.y); r[2]=(short)f2bf(a.z); r[3]=(short)f2bf(a.w);
    r[4]=(short)f2bf(b.x); r[5]=(short)f2bf(b.y); r[6]=(short)f2bf(b.z); r[7]=(short)f2bf(b.w);
    return r;
}

// LDS-only fence barrier: drains ds ops for cross-wave visibility but leaves
// global loads (vmcnt) in flight across the barrier (prefetch survives).
#define LDS_FENCE_BARRIER() do {                                  \
    asm volatile("s_waitcnt lgkmcnt(0)" ::: "memory");            \
    __builtin_amdgcn_s_barrier();                                 \
} while (0)

// ---------------- Phase 1: logits -> softmax -> vlad partials (MFMA bf16) ----
// MFMA 32x32x16 layouts (verified in round 2, absmax 1.2e-4 PASS):
//   A[m][k]: lane m=l&31, k=8*(l>>5)+j ; B[k][n]: lane n=l&31, k=8*(l>>5)+j
//   C/D: col=l&31, row=(r&3)+8*(r>>2)+4*(l>>5)
// LDS 16B-chunk XOR swizzle: chunk' = chunk ^ (row & 7)
__global__ __launch_bounds__(512, 4) void nv_phase1(
    const float* __restrict__ x,      // [B][C][N]
    const float* __restrict__ convw,  // [K][C]
    float* __restrict__ vlad,         // [B][K][C] accumulated via atomics (d_out)
    float* __restrict__ asum_g)       // [B][K]    accumulated via atomics (ws)
{
    __shared__ alignas(16) unsigned short xs[PCH*CC];  // 32 KB bf16 x, [n][c], swizzled
    __shared__ alignas(16) unsigned short xc[CC*PCH];  // 32 KB bf16 x, [c][n], swizzled
    __shared__ float redsm[2][PCH];                    // softmax denom cross-wave
    __shared__ float asred[2][2][16][4];               // [kt][q][r][nt]

    unsigned short* al = xs;   // a[k][n] bf16 (16 KB) aliases xs rows 0..63:
                               // xs dead after logits; al dead before next stage.

    const int t  = threadIdx.x;
    const int b  = blockIdx.y;
    const int n_slab = blockIdx.x * SLAB;
    const int l   = t & 63;
    const int wid = t >> 6;
    const int ln  = l & 31;
    const int q   = l >> 5;
    const int kt  = wid & 1;          // logits k-tile
    const int nt  = wid >> 1;         // logits n-tile
    const int ct  = wid & 3;          // vlad c-tile
    const int kt2 = wid >> 2;         // vlad k-tile
    const int r4  = t & 3;

    const float* xb = x + (size_t)b * CC * NN;
    const int n_ = ln + 32*nt;        // softmax pixel (chunk-local)
    const int c2 = ln + 32*ct;        // vlad A row (channel)
    const int k2 = ln + 32*kt2;       // vlad B row (cluster)

    // ---- prologue: issue chunk-0 staging loads (held packed in regs) ----
    unsigned pf0[8], pf1[8];
#pragma unroll
    for (int i = 0; i < 8; ++i) {
        int u = (t >> 2) + 128 * i, cQ = u >> 5, nQ = u & 31;
        float4 v = *(const float4*)(xb + (size_t)(4*cQ + r4) * NN + n_slab + 4*nQ);
        pf0[i] = f2bf(v.x) | (f2bf(v.y) << 16);
        pf1[i] = f2bf(v.z) | (f2bf(v.w) << 16);
    }

    // ---- preload conv_w fragments (A of logits), reused for all chunks ----
    short8 wfrag[8];
    {
        const float* wr = convw + (size_t)(ln + 32*kt) * CC + 8*q;
#pragma unroll
        for (int cs = 0; cs < 8; ++cs) {
            float4 a  = *(const float4*)(wr + 16*cs);
            float4 bb = *(const float4*)(wr + 16*cs + 4);
            wfrag[cs] = pack8(a, bb);
        }
    }

    f32x16 vacc;
#pragma unroll
    for (int i = 0; i < 16; ++i) vacc[i] = 0.f;
    float asum_l[16];
#pragma unroll
    for (int i = 0; i < 16; ++i) asum_l[i] = 0.f;

#pragma unroll 1
    for (int chk = 0; chk < NCH; ++chk) {
        // ---- A: write xs[n][c] + xc[c][n] from prefetch regs ----
#pragma unroll
        for (int i = 0; i < 8; ++i) {
            int u = (t >> 2) + 128 * i, cQ = u >> 5, nQ = u & 31;
            unsigned d0 = pf0[i], d1 = pf1[i];
            // xc: straight write, 4 consecutive n at row c
            int c = 4*cQ + r4;
            *(uint2*)((char*)xc + c*256 + ((((nQ >> 1) ^ (c & 7)) << 4) | ((nQ & 1) * 8)))
                = make_uint2(d0, d1);
            // xs: quad 4x4 shuffle transpose (verified round 2)
            unsigned q0 = (unsigned)__shfl_xor((int)d0, 1);
            unsigned q1 = (unsigned)__shfl_xor((int)d1, 1);
            unsigned e, f;
            if (r4 & 1) { e = (q0 >> 16) | (d0 & 0xffff0000u);
                          f = (q1 >> 16) | (d1 & 0xffff0000u); }
            else        { e = (d0 & 0xffffu) | (q0 << 16);
                          f = (d1 & 0xffffu) | (q1 << 16); }
            unsigned s2 = (unsigned)__shfl_xor((int)((r4 & 2) ? e : f), 2);
            unsigned w0 = (r4 & 2) ? s2 : e;
            unsigned w1 = (r4 & 2) ? f : s2;
            int nn  = 4*nQ + r4;
            int chp = (cQ >> 1) ^ (nn & 7);
            *(uint2*)((char*)xs + nn*256 + (chp << 4) + (cQ & 1)*8) = make_uint2(w0, w1);
        }
        // ---- B: issue next chunk's staging loads (hidden under C/D/E/F) ----
        if (chk + 1 < NCH) {
            const int gn1 = n_slab + (chk + 1) * PCH;
#pragma unroll
            for (int i = 0; i < 8; ++i) {
                int u = (t >> 2) + 128 * i, cQ = u >> 5, nQ = u & 31;
                float4 v = *(const float4*)(xb + (size_t)(4*cQ + r4) * NN + gn1 + 4*nQ);
                pf0[i] = f2bf(v.x) | (f2bf(v.y) << 16);
                pf1[i] = f2bf(v.z) | (f2bf(v.w) << 16);
            }
        }
        LDS_FENCE_BARRIER();   // #1: xs, xc visible

        // ---- C: logits D[k][n] = W x X ----
        f32x16 lacc;
#pragma unroll
        for (int i = 0; i < 16; ++i) lacc[i] = 0.f;
#pragma unroll
        for (int cs = 0; cs < 8; ++cs) {
            int chp = (2*cs + q) ^ (n_ & 7);
            short8 bf = *(const short8*)((const char*)xs + n_*256 + (chp << 4));
            lacc = __builtin_amdgcn_mfma_f32_32x32x16_bf16(wfrag[cs], bf, lacc, 0, 0, 0);
        }

        // ---- D: softmax over k, no max-sub (|logit| <~ 8, exp safe in fp32) ----
        float ssum = 0.f;
#pragma unroll
        for (int i = 0; i < 16; ++i) { float e2 = __expf(lacc[i]); lacc[i] = e2; ssum += e2; }
        ssum += __shfl_xor(ssum, 32);
        if (q == 0) redsm[kt][n_] = ssum;
        LDS_FENCE_BARRIER();   // #2: denom visible

        // ---- E: scale, store a -> al (aliased), accumulate asum ----
        float inv = 1.0f / (redsm[0][n_] + redsm[1][n_]);
#pragma unroll
        for (int i = 0; i < 16; ++i) {
            float a = lacc[i] * inv;
            asum_l[i] += a;
            int k_ = 32*kt + 4*q + (i & 3) + 8*(i >> 2);
            al[k_*128 + ((((n_ >> 3) ^ (k_ & 7)) << 3) | (n_ & 7))] = (unsigned short)f2bf(a);
        }
        LDS_FENCE_BARRIER();   // #3: al ready

        // ---- F: vlad D[c][k] += X x A^T, both operands from LDS ----
#pragma unroll
        for (int ns = 0; ns < 8; ++ns) {
            int ca = (2*ns + q) ^ (c2 & 7);
            short8 af = *(const short8*)((const char*)xc + c2*256 + (ca << 4));
            int cb = (2*ns + q) ^ (k2 & 7);
            short8 bf = *(const short8*)((const char*)al + k2*256 + (cb << 4));
            vacc = __builtin_amdgcn_mfma_f32_32x32x16_bf16(af, bf, vacc, 0, 0, 0);
        }
        LDS_FENCE_BARRIER();   // #4: LDS free for next chunk's staging writes
    }

    // ---- epilogue: vlad partials -> global atomics ----
    {
        float* vb = vlad + (size_t)b * KK * CC + (size_t)k2 * CC + 32*ct + 4*q;
#pragma unroll
        for (int i = 0; i < 16; ++i)
            atomicAdd(&vb[(i & 3) + 8*(i >> 2)], vacc[i]);
    }

    // ---- asum: butterfly over 32 pixel-lanes, cross-wave LDS, 64 atomics ----
#pragma unroll
    for (int i = 0; i < 16; ++i) {
        float v = asum_l[i];
        v += __shfl_xor(v, 1);  v += __shfl_xor(v, 2);  v += __shfl_xor(v, 4);
        v += __shfl_xor(v, 8);  v += __shfl_xor(v, 16);
        asum_l[i] = v;
    }
    if (ln == 0) {
#pragma unroll
        for (int i = 0; i < 16; ++i) asred[kt][q][i][nt] = asum_l[i];
    }
    __syncthreads();
    if (t < 64) {
        int kt_ = t >> 5, q_ = (t >> 4) & 1, r_ = t & 15;
        int k_ = 32*kt_ + 4*q_ + (r_ & 3) + 8*(r_ >> 2);
        float s = asred[kt_][q_][r_][0] + asred[kt_][q_][r_][1]
                + asred[kt_][q_][r_][2] + asred[kt_][q_][r_][3];
        atomicAdd(&asum_g[b * KK + k_], s);
    }
}

// ---------------- Phase 2: centroid subtract + intra + global L2 normalize ---
__global__ __launch_bounds__(256) void nv_phase2(
    float* __restrict__ vlad,        // [B][K][C] in/out (d_out)
    const float* __restrict__ asum,  // [B][K]
    const float* __restrict__ cent)  // [K][C]
{
    __shared__ float gred[4];
    const int b    = blockIdx.x;
    const int w    = threadIdx.x >> 6;   // wave 0..3 -> 16 rows each
    const int lane = threadIdx.x & 63;

    float v[32];
    float gsum = 0.f;
#pragma unroll
    for (int r = 0; r < 16; r++) {
        int k = w * 16 + r;
        float a  = asum[b * KK + k];
        float x0 = vlad[((size_t)b * KK + k) * CC + lane]      - a * cent[k * CC + lane];
        float x1 = vlad[((size_t)b * KK + k) * CC + lane + 64] - a * cent[k * CC + lane + 64];
        float ss = x0 * x0 + x1 * x1;
#pragma unroll
        for (int m = 1; m < 64; m <<= 1) ss += __shfl_xor(ss, m, 64);
        float rn = 1.0f / fmaxf(sqrtf(ss), 1e-12f);
        v[2 * r]     = x0 * rn;
        v[2 * r + 1] = x1 * rn;
        gsum += ss * rn * rn;
    }
    if (lane == 0) gred[w] = gsum;
    __syncthreads();
    float g  = gred[0] + gred[1] + gred[2] + gred[3];
    float gs = 1.0f / fmaxf(sqrtf(g), 1e-12f);
#pragma unroll
    for (int r = 0; r < 16; r++) {
        int k = w * 16 + r;
        vlad[((size_t)b * KK + k) * CC + lane]      = v[2 * r]     * gs;
        vlad[((size_t)b * KK + k) * CC + lane + 64] = v[2 * r + 1] * gs;
    }
}

extern "C" void kernel_launch(void* const* d_in, const int* in_sizes, int n_in,
                              void* d_out, int out_size, void* d_ws, size_t ws_size,
                              hipStream_t stream) {
    const float* x     = (const float*)d_in[0];
    const float* convw = (const float*)d_in[1];
    const float* cent  = (const float*)d_in[2];
    float* out  = (float*)d_out;
    float* asum = (float*)d_ws;   // B*K floats = 16 KiB

    hipMemsetAsync(out,  0, (size_t)BB * KK * CC * sizeof(float), stream);
    hipMemsetAsync(asum, 0, (size_t)BB * KK * sizeof(float), stream);

    nv_phase1<<<dim3(NN / SLAB, BB), 512, 0, stream>>>(x, convw, out, asum);
    nv_phase2<<<BB, 256, 0, stream>>>(out, asum, cent);
}